// Round 16
// baseline (1005.331 us; speedup 1.0000x reference)
//
#include <hip/hip_runtime.h>
#include <hip/hip_bf16.h>

#define NN 50000
#define EE 800000
#define HH 256
#define GG 128
#define LL 5
#define NCHUNK 196  // ceil((NN+1)/256)
#define BN_EPS 1e-5f

typedef __attribute__((ext_vector_type(8))) short short8_t;
typedef __attribute__((ext_vector_type(4))) float f32x4;
typedef __hip_bfloat16 bf16;

#define AS1 __attribute__((address_space(1)))
#define AS3 __attribute__((address_space(3)))

__device__ __forceinline__ float bf2f(unsigned short u) {
    unsigned int i = ((unsigned int)u) << 16;
    float f;
    __builtin_memcpy(&f, &i, 4);
    return f;
}
__device__ __forceinline__ unsigned short f2bf(float f) {
    bf16 h = __float2bfloat16(f);
    unsigned short u;
    __builtin_memcpy(&u, &h, 2);
    return u;
}

// ---------------- atom encoder ----------------
__global__ __launch_bounds__(256) void k_encode(const int* __restrict__ xf,
                                                const float* __restrict__ atom_emb,
                                                bf16* __restrict__ x) {
    int n = blockIdx.x, h = threadIdx.x;
    float s = 0.f;
#pragma unroll
    for (int f = 0; f < 9; ++f) {
        int v = xf[n * 9 + f];
        s += atom_emb[((size_t)f * 64 + v) * HH + h];
    }
    x[(size_t)n * HH + h] = __float2bfloat16(s);
}

// ---------------- bond combo table (bf16) ----------------
__global__ __launch_bounds__(256) void k_combo(const float* __restrict__ bond_emb,
                                               bf16* __restrict__ table) {
    int c = blockIdx.x, h = threadIdx.x;
    float v = bond_emb[(size_t)((c >> 6) & 7) * HH + h]
            + bond_emb[(size_t)(8 + ((c >> 3) & 7)) * HH + h]
            + bond_emb[(size_t)(16 + (c & 7)) * HH + h];
    table[(size_t)c * HH + h] = __float2bfloat16(v);
}

// ---------------- weight prep: Wt[z][n][k] = bf16(W[z][k][n]) ----------------
__global__ __launch_bounds__(256) void k_prepw(const float* __restrict__ W1,
                                               const float* __restrict__ W2,
                                               const float* __restrict__ oW1,
                                               const float* __restrict__ oW2,
                                               bf16* __restrict__ out) {
    int z = blockIdx.z;
    const float* src = (z < 5) ? W1 + (size_t)z * 65536
                     : (z < 10) ? W2 + (size_t)(z - 5) * 65536
                     : (z == 10) ? oW1 : oW2;
    bf16* dst = out + (size_t)z * 65536;
    __shared__ float tile[32][33];
    int kt = blockIdx.y * 32, nt = blockIdx.x * 32;
    int tx = threadIdx.x, ty = threadIdx.y;  // 32 x 8
    for (int i = ty; i < 32; i += 8) tile[i][tx] = src[(size_t)(kt + i) * 256 + nt + tx];
    __syncthreads();
    for (int i = ty; i < 32; i += 8)
        dst[(size_t)(nt + i) * 256 + kt + tx] = __float2bfloat16(tile[tx][i]);
}

// ---------------- CSR build ----------------
__global__ __launch_bounds__(256) void k_hist(const int* __restrict__ ei, int* __restrict__ deg) {
    int e = blockIdx.x * 256 + threadIdx.x;
    if (e < EE) atomicAdd(&deg[ei[EE + e]], 1);
}

__global__ __launch_bounds__(256) void k_scan_a(const int* __restrict__ deg, int* __restrict__ ro,
                                                int* __restrict__ bsum) {
    __shared__ int sm[256];
    int b = blockIdx.x, t = threadIdx.x;
    int idx = b * 256 + t;
    int v = (idx < NN) ? deg[idx] : 0;
    sm[t] = v;
    __syncthreads();
    for (int off = 1; off < 256; off <<= 1) {
        int add = (t >= off) ? sm[t - off] : 0;
        __syncthreads();
        sm[t] += add;
        __syncthreads();
    }
    if (idx <= NN) ro[idx] = sm[t] - v;
    if (t == 255) bsum[b] = sm[255];
}

__global__ __launch_bounds__(256) void k_scan_b(int* __restrict__ bsum) {
    __shared__ int sm[256];
    int t = threadIdx.x;
    int v = (t < NCHUNK) ? bsum[t] : 0;
    sm[t] = v;
    __syncthreads();
    for (int off = 1; off < 256; off <<= 1) {
        int add = (t >= off) ? sm[t - off] : 0;
        __syncthreads();
        sm[t] += add;
        __syncthreads();
    }
    if (t < NCHUNK) bsum[t] = sm[t] - v;
}

__global__ __launch_bounds__(256) void k_scan_c(int* __restrict__ ro, const int* __restrict__ bsum,
                                                int* __restrict__ cursor) {
    int b = blockIdx.x, t = threadIdx.x;
    int idx = b * 256 + t;
    if (idx <= NN) {
        int val = ro[idx] + bsum[b];
        ro[idx] = val;
        if (idx < NN) cursor[idx] = val;
    }
}

// packed edge: (combo << 16) | src   (src < 50000 < 2^16, combo < 512)
__global__ __launch_bounds__(256) void k_scatter(const int* __restrict__ ei,
                                                 const int* __restrict__ attr,
                                                 int* __restrict__ cursor,
                                                 unsigned int* __restrict__ ebuf) {
    int e0 = blockIdx.x * 512 + threadIdx.x;
#pragma unroll
    for (int r = 0; r < 2; ++r) {
        int e = e0 + r * 256;
        if (e < EE) {
            int d = ei[EE + e];
            unsigned int c = (unsigned int)((attr[e * 3] << 6) | (attr[e * 3 + 1] << 3) | attr[e * 3 + 2]);
            int pos = atomicAdd(&cursor[d], 1);
            ebuf[pos] = (c << 16) | (unsigned int)ei[e];
        }
    }
}

// ---------------- BN+relu materialize (in-place, elementwise) ----------------
__global__ __launch_bounds__(256) void k_bnrelu(bf16* __restrict__ t,
                                                const float* __restrict__ sIn,
                                                const float* __restrict__ qIn,
                                                const float* __restrict__ gIn,
                                                const float* __restrict__ beIn,
                                                float invN) {
    int grp = threadIdx.x >> 6;
    int lane = threadIdx.x & 63;
    int h4 = lane * 4;
    float4 s4 = *(const float4*)(sIn + h4);
    float4 q4 = *(const float4*)(qIn + h4);
    float4 g4 = *(const float4*)(gIn + h4);
    float4 b4 = *(const float4*)(beIn + h4);
    float4 cav, cbv;
#define COEF(C)                                                 \
    { float mu = s4.C * invN;                                   \
      float var = fmaf(-mu, mu, q4.C * invN);                   \
      float a = g4.C * rsqrtf(var + BN_EPS);                    \
      cav.C = a; cbv.C = fmaf(-mu, a, b4.C); }
    COEF(x) COEF(y) COEF(z) COEF(w)
#undef COEF
    int n = blockIdx.x * 4 + grp;
    if (n >= NN) return;
    ushort4 v = *(const ushort4*)(t + (size_t)n * HH + h4);
    ushort4 o;
    o.x = f2bf(fmaxf(fmaf(bf2f(v.x), cav.x, cbv.x), 0.f));
    o.y = f2bf(fmaxf(fmaf(bf2f(v.y), cav.y, cbv.y), 0.f));
    o.z = f2bf(fmaxf(fmaf(bf2f(v.z), cav.z, cbv.z), 0.f));
    o.w = f2bf(fmaxf(fmaf(bf2f(v.w), cav.w, cbv.w), 0.f));
    *(ushort4*)(t + (size_t)n * HH + h4) = o;
}

// ---------------- fused aggregate: split-wave, 4-edge unroll, packed uint32 edges ----------------
__global__ __launch_bounds__(256) void k_aggregate(const bf16* __restrict__ u,
                                                   const int* __restrict__ ro,
                                                   const unsigned int* __restrict__ eb,
                                                   const bf16* __restrict__ combo,
                                                   bf16* __restrict__ aggout) {
    int wid = threadIdx.x >> 6;
    int lane = threadIdx.x & 63;
    int half = lane >> 5;
    int sl = lane & 31;
    int n = blockIdx.x * 4 + wid;
    if (n >= NN) return;
    int h8 = sl * 8;  // 8 bf16 = 16B per lane
    float p0[8] = {0.f, 0.f, 0.f, 0.f, 0.f, 0.f, 0.f, 0.f};
    float p1[8] = {0.f, 0.f, 0.f, 0.f, 0.f, 0.f, 0.f, 0.f};
    int e0 = ro[n], e1 = ro[n + 1];
    int j = e0;
#define ACCUM(P, xs, cs)                                                       \
    {                                                                          \
        unsigned int xw[4] = {xs.x, xs.y, xs.z, xs.w};                         \
        unsigned int cw[4] = {cs.x, cs.y, cs.z, cs.w};                         \
        _Pragma("unroll") for (int q = 0; q < 4; ++q) {                        \
            float xlo = __uint_as_float(xw[q] << 16);                          \
            float xhi = __uint_as_float(xw[q] & 0xffff0000u);                  \
            float clo = __uint_as_float(cw[q] << 16);                          \
            float chi = __uint_as_float(cw[q] & 0xffff0000u);                  \
            P[2 * q] += fmaxf(xlo + clo, 0.f);                                 \
            P[2 * q + 1] += fmaxf(xhi + chi, 0.f);                             \
        }                                                                      \
    }
    for (; j + 4 <= e1; j += 4) {
        unsigned int rA = eb[j + half];
        unsigned int rB = eb[j + 2 + half];
        uint4 xA = *(const uint4*)(u + (size_t)(rA & 0xffffu) * HH + h8);
        uint4 cA = *(const uint4*)(combo + ((size_t)(rA >> 16) << 8) + h8);
        uint4 xB = *(const uint4*)(u + (size_t)(rB & 0xffffu) * HH + h8);
        uint4 cB = *(const uint4*)(combo + ((size_t)(rB >> 16) << 8) + h8);
        ACCUM(p0, xA, cA);
        ACCUM(p1, xB, cB);
    }
    for (; j < e1; j += 2) {
        int idx = j + half;
        bool v = idx < e1;
        unsigned int r = eb[v ? idx : e0];
        uint4 xA = *(const uint4*)(u + (size_t)(r & 0xffffu) * HH + h8);
        uint4 cA = *(const uint4*)(combo + ((size_t)(r >> 16) << 8) + h8);
        if (v) ACCUM(p0, xA, cA);
    }
#undef ACCUM
#pragma unroll
    for (int i = 0; i < 8; ++i) {
        p0[i] += p1[i];
        p0[i] += __shfl_xor(p0[i], 32);
    }
    if (half == 0) {
        uint4 tv = *(const uint4*)(u + (size_t)n * HH + h8);
        unsigned int tw[4] = {tv.x, tv.y, tv.z, tv.w};
        unsigned int ow[4];
#pragma unroll
        for (int q = 0; q < 4; ++q) {
            float tlo = __uint_as_float(tw[q] << 16);
            float thi = __uint_as_float(tw[q] & 0xffff0000u);
            ow[q] = (unsigned int)f2bf(p0[2 * q] + tlo)
                  | ((unsigned int)f2bf(p0[2 * q + 1] + thi) << 16);
        }
        *(uint4*)(aggout + (size_t)n * HH + h8) = make_uint4(ow[0], ow[1], ow[2], ow[3]);
    }
}

// ---------------- GEMM F v2 (barrier-light): Out = A @ W + bias (+ stats) ----------------
// BM=128, BN=256, 512 thr / 8 waves (4 row x 2 col; 32x128 per wave).
// W processed in two K=128 half-panels, each fully LDS-resident (64 KB, single-buffered):
//   {barrier; stage half; barrier; 4 barrier-FREE K-steps (A via private VGPR prefetch)}.
// 3 barrier drains total (vs 8). A rows read 2x (both col-waves, same block, L2-hot).
__global__ __launch_bounds__(512, 4) void k_gemmF(const bf16* __restrict__ A,
                                                  const bf16* __restrict__ Wt,
                                                  const float* __restrict__ bias,
                                                  bf16* __restrict__ Out,
                                                  int M,
                                                  float* __restrict__ ssum,
                                                  float* __restrict__ ssq) {
    __shared__ uint4 Lb[4096];  // 64 KB: chunk = kgl*256 + col, kgl = (k - ph*128)/8 in [0,16)
    const int t = threadIdx.x;
    const int lane = t & 63;
    const int w = t >> 6;                 // 0..7
    const int wr = w >> 1, wc = w & 1;    // 4 x 2 wave grid
    const int m0 = blockIdx.x * 128;
    const int lhi = lane >> 4, llo = lane & 15;

    // B staging: thread covers chunks (skg0 + i*2)*256 + scol, i = 0..7
    const int scol = ((w & 3) << 6) + lane;   // 0..255 (w&3 spans 0..3 twice; lane 0..63)
    const int skg0 = w >> 2;                  // 0 or 1
    const int sbase = ((w & 3) << 6);         // wave-uniform LDS col base

    // A fragment rows: m0 + wr*32 + m*16 + llo, m = 0,1; 16B at k = lhi*8
    const size_t arow0 = (size_t)(m0 + wr * 32 + llo) * HH + lhi * 8;
    const size_t arow1 = arow0 + (size_t)16 * HH;

    f32x4 acc[2][8] = {};
    uint4 a0 = *(const uint4*)(A + arow0);
    uint4 a1 = *(const uint4*)(A + arow1);
    uint4 n0_, n1_;

    for (int ph = 0; ph < 2; ++ph) {
        if (ph) __syncthreads();  // all waves done reading Lb before overwrite
#pragma unroll
        for (int i = 0; i < 8; ++i) {
            const int kgl = skg0 + i * 2;
            const bf16* src = Wt + (size_t)scol * HH + ph * 128 + kgl * 8;
            __builtin_amdgcn_global_load_lds((const AS1 void*)src,
                                             (AS3 void*)&Lb[kgl * 256 + sbase], 16, 0, 0);
        }
        __syncthreads();          // B half resident
#pragma unroll
        for (int s = 0; s < 4; ++s) {
            const int gs = ph * 4 + s;
            if (gs < 7) {
                n0_ = *(const uint4*)(A + arow0 + (gs + 1) * 32);
                n1_ = *(const uint4*)(A + arow1 + (gs + 1) * 32);
            }
            short8_t af[2], bfv[8];
            __builtin_memcpy(&af[0], &a0, 16);
            __builtin_memcpy(&af[1], &a1, 16);
#pragma unroll
            for (int n = 0; n < 8; ++n)
                bfv[n] = *(const short8_t*)&Lb[(s * 4 + lhi) * 256 + wc * 128 + n * 16 + llo];
#pragma unroll
            for (int m = 0; m < 2; ++m)
#pragma unroll
                for (int n = 0; n < 8; ++n)
                    acc[m][n] = __builtin_amdgcn_mfma_f32_16x16x32_bf16(af[m], bfv[n], acc[m][n], 0, 0, 0);
            if (gs < 7) { a0 = n0_; a1 = n1_; }
        }
    }

    // epilogue: bias, store bf16, column stats
    float bias_n[8];
    int col_n[8];
#pragma unroll
    for (int n = 0; n < 8; ++n) {
        col_n[n] = wc * 128 + n * 16 + llo;
        bias_n[n] = bias[col_n[n]];
    }
    float ps[8] = {0.f, 0.f, 0.f, 0.f, 0.f, 0.f, 0.f, 0.f};
    float pq[8] = {0.f, 0.f, 0.f, 0.f, 0.f, 0.f, 0.f, 0.f};
#pragma unroll
    for (int m = 0; m < 2; ++m) {
#pragma unroll
        for (int j = 0; j < 4; ++j) {
            int row = m0 + wr * 32 + m * 16 + lhi * 4 + j;
            bool valid = row < M;
#pragma unroll
            for (int n = 0; n < 8; ++n) {
                float v = acc[m][n][j] + bias_n[n];
                if (valid) {
                    Out[(size_t)row * HH + col_n[n]] = __float2bfloat16(v);
                    ps[n] += v;
                    pq[n] = fmaf(v, v, pq[n]);
                }
            }
        }
    }
#pragma unroll
    for (int n = 0; n < 8; ++n) {
        float s = ps[n];
        s += __shfl_xor(s, 16);
        s += __shfl_xor(s, 32);
        float q = pq[n];
        q += __shfl_xor(q, 16);
        q += __shfl_xor(q, 32);
        if (lhi == 0) {
            atomicAdd(&ssum[col_n[n]], s);
            atomicAdd(&ssq[col_n[n]], q);
        }
    }
}

// ---------------- MFMA GEMM T (R12-proven): Out = T(A) @ W + bias ----------------
struct GLds {
    uint4 a[2][512];   // [kg*128 + row]
    uint4 b[2][1024];  // [kg*256 + col]
    float ca[256], cb[256];
};

__device__ __forceinline__ uint4 xchunk(uint4 u, const float* ca, const float* cb, int k0) {
    float4 ca0 = *(const float4*)(ca + k0);
    float4 ca1 = *(const float4*)(ca + k0 + 4);
    float4 cb0 = *(const float4*)(cb + k0);
    float4 cb1 = *(const float4*)(cb + k0 + 4);
    float cav[8] = {ca0.x, ca0.y, ca0.z, ca0.w, ca1.x, ca1.y, ca1.z, ca1.w};
    float cbv[8] = {cb0.x, cb0.y, cb0.z, cb0.w, cb1.x, cb1.y, cb1.z, cb1.w};
    unsigned int s[4] = {u.x, u.y, u.z, u.w};
#pragma unroll
    for (int p = 0; p < 4; ++p) {
        float lo = bf2f((unsigned short)(s[p] & 0xffffu));
        float hi = bf2f((unsigned short)(s[p] >> 16));
        lo = fmaxf(fmaf(lo, cav[2 * p], cbv[2 * p]), 0.f);
        hi = fmaxf(fmaf(hi, cav[2 * p + 1], cbv[2 * p + 1]), 0.f);
        s[p] = (unsigned int)f2bf(lo) | ((unsigned int)f2bf(hi) << 16);
    }
    return make_uint4(s[0], s[1], s[2], s[3]);
}

template <bool POOL>
__global__ __launch_bounds__(512, 4) void k_gemmT(const bf16* __restrict__ A,
                                                  const bf16* __restrict__ Wt,
                                                  const float* __restrict__ bias,
                                                  bf16* __restrict__ Out,
                                                  int M, int do_relu,
                                                  const float* __restrict__ sIn,
                                                  const float* __restrict__ qIn,
                                                  const float* __restrict__ gIn,
                                                  const float* __restrict__ beIn,
                                                  float invN,
                                                  float* __restrict__ ssum,
                                                  float* __restrict__ ssq,
                                                  const int* __restrict__ pbatch,
                                                  float* __restrict__ pout) {
    __shared__ GLds L;
    const int t = threadIdx.x;
    const int lane = t & 63;
    const int w = t >> 6;
    const int wr = w >> 2, wc = w & 3;
    const int m0 = blockIdx.x * 128;
    const int lhi = lane >> 4, llo = lane & 15;

    if (t < 256) {
        float mu = sIn[t] * invN;
        float var = fmaf(-mu, mu, qIn[t] * invN);
        float a = gIn[t] * rsqrtf(var + BN_EPS);
        L.ca[t] = a;
        L.cb[t] = fmaf(-mu, a, beIn[t]);
    }
    __syncthreads();

    const int arow_i = t & 127, akg = t >> 7;
    const bf16* aptr = A + (size_t)(m0 + arow_i) * HH + akg * 8;
    const int bcol = wc * 64 + lane;
    const bf16* bptr = Wt + (size_t)bcol * HH + wr * 8;

    f32x4 acc[4][4] = {};
    uint4 areg, anext;

#define STAGE_B(c, kb)                                                                        \
    _Pragma("unroll") for (int q = 0; q < 2; ++q) {                                           \
        __builtin_amdgcn_global_load_lds((const AS1 void*)(bptr + (kb) + q * 16),             \
                                         (AS3 void*)&L.b[c][q * 512 + w * 64], 16, 0, 0);     \
    }

    STAGE_B(0, 0);
    areg = *(const uint4*)(aptr + 0);
    L.a[0][t] = xchunk(areg, L.ca, L.cb, akg * 8);
    __syncthreads();

    int c = 0;
    for (int step = 0; step < 8; ++step) {
        const int kn = (step + 1) * 32;
        if (step < 7) {
            STAGE_B(c ^ 1, kn);
            anext = *(const uint4*)(aptr + kn);
        }
        short8_t af[4], bfv[4];
#pragma unroll
        for (int m = 0; m < 4; ++m)
            af[m] = *(const short8_t*)&L.a[c][lhi * 128 + wr * 64 + m * 16 + llo];
#pragma unroll
        for (int n = 0; n < 4; ++n)
            bfv[n] = *(const short8_t*)&L.b[c][lhi * 256 + wc * 64 + n * 16 + llo];
#pragma unroll
        for (int m = 0; m < 4; ++m)
#pragma unroll
            for (int n = 0; n < 4; ++n)
                acc[m][n] = __builtin_amdgcn_mfma_f32_16x16x32_bf16(af[m], bfv[n], acc[m][n], 0, 0, 0);
        if (step < 7)
            L.a[c ^ 1][t] = xchunk(anext, L.ca, L.cb, kn + akg * 8);
        __syncthreads();
        c ^= 1;
    }
#undef STAGE_B

    float bias_n[4];
    int col_n[4];
#pragma unroll
    for (int n = 0; n < 4; ++n) {
        col_n[n] = wc * 64 + n * 16 + llo;
        bias_n[n] = bias[col_n[n]];
    }

    if (POOL) {
        int gcur = -1;
        float pacc[4] = {0.f, 0.f, 0.f, 0.f};
#pragma unroll
        for (int m = 0; m < 4; ++m) {
#pragma unroll
            for (int j = 0; j < 4; ++j) {
                int row = m0 + wr * 64 + m * 16 + lhi * 4 + j;
                if (row < M) {
                    int g = pbatch[row];
                    if (g != gcur) {
                        if (gcur >= 0) {
#pragma unroll
                            for (int n = 0; n < 4; ++n)
                                atomicAdd(&pout[(size_t)gcur * HH + col_n[n]], pacc[n]);
                        }
                        gcur = g;
#pragma unroll
                        for (int n = 0; n < 4; ++n) pacc[n] = 0.f;
                    }
#pragma unroll
                    for (int n = 0; n < 4; ++n)
                        pacc[n] += acc[m][n][j] + bias_n[n];
                }
            }
        }
        if (gcur >= 0) {
#pragma unroll
            for (int n = 0; n < 4; ++n)
                atomicAdd(&pout[(size_t)gcur * HH + col_n[n]], pacc[n]);
        }
        return;
    }

    float ps[4] = {0.f, 0.f, 0.f, 0.f}, pq[4] = {0.f, 0.f, 0.f, 0.f};
#pragma unroll
    for (int m = 0; m < 4; ++m) {
#pragma unroll
        for (int j = 0; j < 4; ++j) {
            int row = m0 + wr * 64 + m * 16 + lhi * 4 + j;
            bool valid = row < M;
#pragma unroll
            for (int n = 0; n < 4; ++n) {
                float v = acc[m][n][j] + bias_n[n];
                if (do_relu) v = fmaxf(v, 0.f);
                if (valid) {
                    Out[(size_t)row * HH + col_n[n]] = __float2bfloat16(v);
                    ps[n] += v;
                    pq[n] = fmaf(v, v, pq[n]);
                }
            }
        }
    }

    if (ssum) {
#pragma unroll
        for (int n = 0; n < 4; ++n) {
            float s = ps[n];
            s += __shfl_xor(s, 16);
            s += __shfl_xor(s, 32);
            float q = pq[n];
            q += __shfl_xor(q, 16);
            q += __shfl_xor(q, 32);
            if (lhi == 0) {
                atomicAdd(&ssum[col_n[n]], s);
                atomicAdd(&ssq[col_n[n]], q);
            }
        }
    }
}

static size_t align256(size_t v) { return (v + 255) & ~(size_t)255; }

extern "C" void kernel_launch(void* const* d_in, const int* in_sizes, int n_in,
                              void* d_out, int out_size, void* d_ws, size_t ws_size,
                              hipStream_t stream) {
    const int* x_feat = (const int*)d_in[0];
    const int* ei = (const int*)d_in[1];
    const int* attr = (const int*)d_in[2];
    const int* batch = (const int*)d_in[3];
    const float* atom_emb = (const float*)d_in[4];
    const float* bond_emb = (const float*)d_in[5];
    const float* W1 = (const float*)d_in[6];
    const float* b1 = (const float*)d_in[7];
    const float* g1 = (const float*)d_in[8];
    const float* be1 = (const float*)d_in[9];
    const float* W2 = (const float*)d_in[10];
    const float* b2 = (const float*)d_in[11];
    const float* g2 = (const float*)d_in[12];
    const float* be2 = (const float*)d_in[13];
    const float* outW1 = (const float*)d_in[14];
    const float* outb1 = (const float*)d_in[15];
    const float* outg = (const float*)d_in[16];
    const float* outbe = (const float*)d_in[17];
    const float* outW2 = (const float*)d_in[18];
    const float* outb2 = (const float*)d_in[19];
    float* out = (float*)d_out;

    char* ws = (char*)d_ws;
    const size_t BUF_STRIDE = align256((size_t)NN * HH * 2 + 131072);  // bf16 + GEMM OOB pad
    bf16* bufA = (bf16*)ws;                       // t / node features
    bf16* bufB = (bf16*)(ws + BUF_STRIDE);        // agg
    bf16* bufC = (bf16*)(ws + 2 * BUF_STRIDE);    // y
    char* p = ws + 3 * BUF_STRIDE;
    unsigned int* ebuf = (unsigned int*)p;  p += align256((size_t)EE * sizeof(unsigned int));
    int* deg = (int*)p;
    float* stats = (float*)(p + (size_t)NN * sizeof(int));  // [11][2][256]
    const size_t ZERO_BYTES = (size_t)NN * sizeof(int) + 11 * 512 * sizeof(float);
    p += align256(ZERO_BYTES);
    int* ro = (int*)p;                p += align256((size_t)(NN + 1) * sizeof(int));
    int* cursor = (int*)p;            p += align256((size_t)NN * sizeof(int));
    int* bsum = (int*)p;              p += align256(256 * sizeof(int));
    bf16* combo = (bf16*)p;           p += align256((size_t)512 * HH * sizeof(bf16));
    bf16* wbuf = (bf16*)p;            p += align256((size_t)12 * 65536 * sizeof(bf16));

    const float invN = 1.0f / (float)NN;
    const int EBLK = (EE + 255) / 256;
    const int GBLK = (NN + 127) / 128;   // 391
    const int AGG_GRID = (NN + 3) / 4;
    const int BNR_GRID = (NN + 3) / 4;

    // --- one-time prep ---
    hipMemsetAsync(deg, 0, ZERO_BYTES, stream);
    hipMemsetAsync(d_out, 0, (size_t)GG * HH * sizeof(float), stream);
    k_hist<<<EBLK, 256, 0, stream>>>(ei, deg);
    k_scan_a<<<NCHUNK, 256, 0, stream>>>(deg, ro, bsum);
    k_scan_b<<<1, 256, 0, stream>>>(bsum);
    k_scan_c<<<NCHUNK, 256, 0, stream>>>(ro, bsum, cursor);
    k_scatter<<<(EE + 511) / 512, 256, 0, stream>>>(ei, attr, cursor, ebuf);
    k_combo<<<512, 256, 0, stream>>>(bond_emb, combo);
    k_prepw<<<dim3(8, 8, 12), dim3(32, 8), 0, stream>>>(W1, W2, outW1, outW2, wbuf);
    k_encode<<<NN, 256, 0, stream>>>(x_feat, atom_emb, bufA);

    for (int l = 0; l < LL; ++l) {
        float* s1 = stats + (size_t)(2 * l) * 512;
        float* q1 = s1 + 256;
        float* s2 = stats + (size_t)(2 * l + 1) * 512;
        float* q2 = s2 + 256;
        if (l > 0) {
            float* sp = stats + (size_t)(2 * l - 1) * 512;
            k_bnrelu<<<BNR_GRID, 256, 0, stream>>>(bufA, sp, sp + 256,
                                                   g2 + (size_t)(l - 1) * HH,
                                                   be2 + (size_t)(l - 1) * HH, invN);
        }
        k_aggregate<<<AGG_GRID, 256, 0, stream>>>(bufA, ro, ebuf, combo, bufB);
        // y = agg @ W1 + b1   (+ stats for bn1)
        k_gemmF<<<GBLK, 512, 0, stream>>>(bufB, wbuf + (size_t)l * 65536,
                                          b1 + (size_t)l * HH, bufC, NN, s1, q1);
        // t' = relu(T1(y) @ W2 + b2)   (+ stats for bn2)
        k_gemmT<false><<<GBLK, 512, 0, stream>>>(bufC, wbuf + (size_t)(5 + l) * 65536,
                                                 b2 + (size_t)l * HH, bufA, NN, 1,
                                                 s1, q1, g1 + (size_t)l * HH,
                                                 be1 + (size_t)l * HH, invN, s2, q2,
                                                 nullptr, nullptr);
    }

    // --- head ---
    float* sP = stats + (size_t)9 * 512;   // layer-4 bn2 stats
    float* sH = stats + (size_t)10 * 512;
    float* qH = sH + 256;
    // y = T2(t5) @ outW1 + outb1 (+ stats sH)
    k_gemmT<false><<<GBLK, 512, 0, stream>>>(bufA, wbuf + (size_t)10 * 65536, outb1,
                                             bufB, NN, 0, sP, sP + 256,
                                             g2 + (size_t)4 * HH, be2 + (size_t)4 * HH,
                                             invN, sH, qH, nullptr, nullptr);
    // z = T_H(y) @ outW2 + outb2, pooled directly into out
    k_gemmT<true><<<GBLK, 512, 0, stream>>>(bufB, wbuf + (size_t)11 * 65536, outb2,
                                            bufC, NN, 0, sH, qH, outg, outbe,
                                            invN, nullptr, nullptr, batch, out);
}

// Round 17
// 927.466 us; speedup vs baseline: 1.0840x; 1.0840x over previous
//
#include <hip/hip_runtime.h>
#include <hip/hip_bf16.h>

#define NN 50000
#define EE 800000
#define HH 256
#define GG 128
#define LL 5
#define NCHUNK 196  // ceil((NN+1)/256)
#define BN_EPS 1e-5f

typedef __attribute__((ext_vector_type(8))) short short8_t;
typedef __attribute__((ext_vector_type(4))) float f32x4;
typedef __hip_bfloat16 bf16;

#define AS1 __attribute__((address_space(1)))
#define AS3 __attribute__((address_space(3)))

__device__ __forceinline__ float bf2f(unsigned short u) {
    unsigned int i = ((unsigned int)u) << 16;
    float f;
    __builtin_memcpy(&f, &i, 4);
    return f;
}
__device__ __forceinline__ unsigned short f2bf(float f) {
    bf16 h = __float2bfloat16(f);
    unsigned short u;
    __builtin_memcpy(&u, &h, 2);
    return u;
}

// ---------------- atom encoder ----------------
__global__ __launch_bounds__(256) void k_encode(const int* __restrict__ xf,
                                                const float* __restrict__ atom_emb,
                                                bf16* __restrict__ x) {
    int n = blockIdx.x, h = threadIdx.x;
    float s = 0.f;
#pragma unroll
    for (int f = 0; f < 9; ++f) {
        int v = xf[n * 9 + f];
        s += atom_emb[((size_t)f * 64 + v) * HH + h];
    }
    x[(size_t)n * HH + h] = __float2bfloat16(s);
}

// ---------------- bond combo table (bf16) ----------------
__global__ __launch_bounds__(256) void k_combo(const float* __restrict__ bond_emb,
                                               bf16* __restrict__ table) {
    int c = blockIdx.x, h = threadIdx.x;
    float v = bond_emb[(size_t)((c >> 6) & 7) * HH + h]
            + bond_emb[(size_t)(8 + ((c >> 3) & 7)) * HH + h]
            + bond_emb[(size_t)(16 + (c & 7)) * HH + h];
    table[(size_t)c * HH + h] = __float2bfloat16(v);
}

// ---------------- weight prep: Wt[z][n][k] = bf16(W[z][k][n]) ----------------
__global__ __launch_bounds__(256) void k_prepw(const float* __restrict__ W1,
                                               const float* __restrict__ W2,
                                               const float* __restrict__ oW1,
                                               const float* __restrict__ oW2,
                                               bf16* __restrict__ out) {
    int z = blockIdx.z;
    const float* src = (z < 5) ? W1 + (size_t)z * 65536
                     : (z < 10) ? W2 + (size_t)(z - 5) * 65536
                     : (z == 10) ? oW1 : oW2;
    bf16* dst = out + (size_t)z * 65536;
    __shared__ float tile[32][33];
    int kt = blockIdx.y * 32, nt = blockIdx.x * 32;
    int tx = threadIdx.x, ty = threadIdx.y;  // 32 x 8
    for (int i = ty; i < 32; i += 8) tile[i][tx] = src[(size_t)(kt + i) * 256 + nt + tx];
    __syncthreads();
    for (int i = ty; i < 32; i += 8)
        dst[(size_t)(nt + i) * 256 + kt + tx] = __float2bfloat16(tile[tx][i]);
}

// ---------------- CSR build ----------------
__global__ __launch_bounds__(256) void k_hist(const int* __restrict__ ei, int* __restrict__ deg) {
    int e = blockIdx.x * 256 + threadIdx.x;
    if (e < EE) atomicAdd(&deg[ei[EE + e]], 1);
}

__global__ __launch_bounds__(256) void k_scan_a(const int* __restrict__ deg, int* __restrict__ ro,
                                                int* __restrict__ bsum) {
    __shared__ int sm[256];
    int b = blockIdx.x, t = threadIdx.x;
    int idx = b * 256 + t;
    int v = (idx < NN) ? deg[idx] : 0;
    sm[t] = v;
    __syncthreads();
    for (int off = 1; off < 256; off <<= 1) {
        int add = (t >= off) ? sm[t - off] : 0;
        __syncthreads();
        sm[t] += add;
        __syncthreads();
    }
    if (idx <= NN) ro[idx] = sm[t] - v;
    if (t == 255) bsum[b] = sm[255];
}

__global__ __launch_bounds__(256) void k_scan_b(int* __restrict__ bsum) {
    __shared__ int sm[256];
    int t = threadIdx.x;
    int v = (t < NCHUNK) ? bsum[t] : 0;
    sm[t] = v;
    __syncthreads();
    for (int off = 1; off < 256; off <<= 1) {
        int add = (t >= off) ? sm[t - off] : 0;
        __syncthreads();
        sm[t] += add;
        __syncthreads();
    }
    if (t < NCHUNK) bsum[t] = sm[t] - v;
}

__global__ __launch_bounds__(256) void k_scan_c(int* __restrict__ ro, const int* __restrict__ bsum,
                                                int* __restrict__ cursor) {
    int b = blockIdx.x, t = threadIdx.x;
    int idx = b * 256 + t;
    if (idx <= NN) {
        int val = ro[idx] + bsum[b];
        ro[idx] = val;
        if (idx < NN) cursor[idx] = val;
    }
}

// packed edge: (combo << 16) | src   (src < 50000 < 2^16, combo < 512)
__global__ __launch_bounds__(256) void k_scatter(const int* __restrict__ ei,
                                                 const int* __restrict__ attr,
                                                 int* __restrict__ cursor,
                                                 unsigned int* __restrict__ ebuf) {
    int e0 = blockIdx.x * 512 + threadIdx.x;
#pragma unroll
    for (int r = 0; r < 2; ++r) {
        int e = e0 + r * 256;
        if (e < EE) {
            int d = ei[EE + e];
            unsigned int c = (unsigned int)((attr[e * 3] << 6) | (attr[e * 3 + 1] << 3) | attr[e * 3 + 2]);
            int pos = atomicAdd(&cursor[d], 1);
            ebuf[pos] = (c << 16) | (unsigned int)ei[e];
        }
    }
}

// ---------------- BN+relu materialize (in-place, elementwise) ----------------
__global__ __launch_bounds__(256) void k_bnrelu(bf16* __restrict__ t,
                                                const float* __restrict__ sIn,
                                                const float* __restrict__ qIn,
                                                const float* __restrict__ gIn,
                                                const float* __restrict__ beIn,
                                                float invN) {
    int grp = threadIdx.x >> 6;
    int lane = threadIdx.x & 63;
    int h4 = lane * 4;
    float4 s4 = *(const float4*)(sIn + h4);
    float4 q4 = *(const float4*)(qIn + h4);
    float4 g4 = *(const float4*)(gIn + h4);
    float4 b4 = *(const float4*)(beIn + h4);
    float4 cav, cbv;
#define COEF(C)                                                 \
    { float mu = s4.C * invN;                                   \
      float var = fmaf(-mu, mu, q4.C * invN);                   \
      float a = g4.C * rsqrtf(var + BN_EPS);                    \
      cav.C = a; cbv.C = fmaf(-mu, a, b4.C); }
    COEF(x) COEF(y) COEF(z) COEF(w)
#undef COEF
    int n = blockIdx.x * 4 + grp;
    if (n >= NN) return;
    ushort4 v = *(const ushort4*)(t + (size_t)n * HH + h4);
    ushort4 o;
    o.x = f2bf(fmaxf(fmaf(bf2f(v.x), cav.x, cbv.x), 0.f));
    o.y = f2bf(fmaxf(fmaf(bf2f(v.y), cav.y, cbv.y), 0.f));
    o.z = f2bf(fmaxf(fmaf(bf2f(v.z), cav.z, cbv.z), 0.f));
    o.w = f2bf(fmaxf(fmaf(bf2f(v.w), cav.w, cbv.w), 0.f));
    *(ushort4*)(t + (size_t)n * HH + h4) = o;
}

// ---------------- fused aggregate: split-wave, 4-edge unroll, packed uint32 edges ----------------
__global__ __launch_bounds__(256) void k_aggregate(const bf16* __restrict__ u,
                                                   const int* __restrict__ ro,
                                                   const unsigned int* __restrict__ eb,
                                                   const bf16* __restrict__ combo,
                                                   bf16* __restrict__ aggout) {
    int wid = threadIdx.x >> 6;
    int lane = threadIdx.x & 63;
    int half = lane >> 5;
    int sl = lane & 31;
    int n = blockIdx.x * 4 + wid;
    if (n >= NN) return;
    int h8 = sl * 8;  // 8 bf16 = 16B per lane
    float p0[8] = {0.f, 0.f, 0.f, 0.f, 0.f, 0.f, 0.f, 0.f};
    float p1[8] = {0.f, 0.f, 0.f, 0.f, 0.f, 0.f, 0.f, 0.f};
    int e0 = ro[n], e1 = ro[n + 1];
    int j = e0;
#define ACCUM(P, xs, cs)                                                       \
    {                                                                          \
        unsigned int xw[4] = {xs.x, xs.y, xs.z, xs.w};                         \
        unsigned int cw[4] = {cs.x, cs.y, cs.z, cs.w};                         \
        _Pragma("unroll") for (int q = 0; q < 4; ++q) {                        \
            float xlo = __uint_as_float(xw[q] << 16);                          \
            float xhi = __uint_as_float(xw[q] & 0xffff0000u);                  \
            float clo = __uint_as_float(cw[q] << 16);                          \
            float chi = __uint_as_float(cw[q] & 0xffff0000u);                  \
            P[2 * q] += fmaxf(xlo + clo, 0.f);                                 \
            P[2 * q + 1] += fmaxf(xhi + chi, 0.f);                             \
        }                                                                      \
    }
    for (; j + 4 <= e1; j += 4) {
        unsigned int rA = eb[j + half];
        unsigned int rB = eb[j + 2 + half];
        uint4 xA = *(const uint4*)(u + (size_t)(rA & 0xffffu) * HH + h8);
        uint4 cA = *(const uint4*)(combo + ((size_t)(rA >> 16) << 8) + h8);
        uint4 xB = *(const uint4*)(u + (size_t)(rB & 0xffffu) * HH + h8);
        uint4 cB = *(const uint4*)(combo + ((size_t)(rB >> 16) << 8) + h8);
        ACCUM(p0, xA, cA);
        ACCUM(p1, xB, cB);
    }
    for (; j < e1; j += 2) {
        int idx = j + half;
        bool v = idx < e1;
        unsigned int r = eb[v ? idx : e0];
        uint4 xA = *(const uint4*)(u + (size_t)(r & 0xffffu) * HH + h8);
        uint4 cA = *(const uint4*)(combo + ((size_t)(r >> 16) << 8) + h8);
        if (v) ACCUM(p0, xA, cA);
    }
#undef ACCUM
#pragma unroll
    for (int i = 0; i < 8; ++i) {
        p0[i] += p1[i];
        p0[i] += __shfl_xor(p0[i], 32);
    }
    if (half == 0) {
        uint4 tv = *(const uint4*)(u + (size_t)n * HH + h8);
        unsigned int tw[4] = {tv.x, tv.y, tv.z, tv.w};
        unsigned int ow[4];
#pragma unroll
        for (int q = 0; q < 4; ++q) {
            float tlo = __uint_as_float(tw[q] << 16);
            float thi = __uint_as_float(tw[q] & 0xffff0000u);
            ow[q] = (unsigned int)f2bf(p0[2 * q] + tlo)
                  | ((unsigned int)f2bf(p0[2 * q + 1] + thi) << 16);
        }
        *(uint4*)(aggout + (size_t)n * HH + h8) = make_uint4(ow[0], ow[1], ow[2], ow[3]);
    }
}

// ---------------- MFMA GEMM (R12/R15-proven): Out[M,256] = T(A)[M,256] @ W + bias ----------------
// BM=128, BN=256, BK=32, 512 threads / 8 waves (2 row x 4 col), double-buffered.
// !HAS_T: A and B via global_load_lds DMA (each A row read exactly once).
// HAS_T: A reg-staged + BN+relu transform once/elem, write-late (T14).
// POOL: epilogue run-length segment-sum into pout[g][col] (batch sorted), no store.
struct GLds {
    uint4 a[2][512];   // [kg*128 + row] : A[row, kb+kg*8 .. +8]
    uint4 b[2][1024];  // [kg*256 + col] : Wt[col, kb+kg*8 .. +8]
    float ca[256], cb[256];
};

__device__ __forceinline__ uint4 xchunk(uint4 u, const float* ca, const float* cb, int k0) {
    float4 ca0 = *(const float4*)(ca + k0);
    float4 ca1 = *(const float4*)(ca + k0 + 4);
    float4 cb0 = *(const float4*)(cb + k0);
    float4 cb1 = *(const float4*)(cb + k0 + 4);
    float cav[8] = {ca0.x, ca0.y, ca0.z, ca0.w, ca1.x, ca1.y, ca1.z, ca1.w};
    float cbv[8] = {cb0.x, cb0.y, cb0.z, cb0.w, cb1.x, cb1.y, cb1.z, cb1.w};
    unsigned int s[4] = {u.x, u.y, u.z, u.w};
#pragma unroll
    for (int p = 0; p < 4; ++p) {
        float lo = bf2f((unsigned short)(s[p] & 0xffffu));
        float hi = bf2f((unsigned short)(s[p] >> 16));
        lo = fmaxf(fmaf(lo, cav[2 * p], cbv[2 * p]), 0.f);
        hi = fmaxf(fmaf(hi, cav[2 * p + 1], cbv[2 * p + 1]), 0.f);
        s[p] = (unsigned int)f2bf(lo) | ((unsigned int)f2bf(hi) << 16);
    }
    return make_uint4(s[0], s[1], s[2], s[3]);
}

template <bool HAS_T, bool POOL>
__global__ __launch_bounds__(512, 4) void k_gemm(const bf16* __restrict__ A,
                                                 const bf16* __restrict__ Wt,
                                                 const float* __restrict__ bias,
                                                 bf16* __restrict__ Out,
                                                 int M, int do_relu,
                                                 const float* __restrict__ sIn,
                                                 const float* __restrict__ qIn,
                                                 const float* __restrict__ gIn,
                                                 const float* __restrict__ beIn,
                                                 float invN,
                                                 float* __restrict__ ssum,
                                                 float* __restrict__ ssq,
                                                 const int* __restrict__ pbatch,
                                                 float* __restrict__ pout) {
    __shared__ GLds L;
    const int t = threadIdx.x;            // 0..511
    const int lane = t & 63;
    const int w = t >> 6;                 // 0..7
    const int wr = w >> 2, wc = w & 3;    // 2 x 4 wave grid
    const int m0 = blockIdx.x * 128;
    const int lhi = lane >> 4, llo = lane & 15;

    if (HAS_T) {
        if (t < 256) {
            float mu = sIn[t] * invN;
            float var = fmaf(-mu, mu, qIn[t] * invN);
            float a = gIn[t] * rsqrtf(var + BN_EPS);
            L.ca[t] = a;
            L.cb[t] = fmaf(-mu, a, beIn[t]);
        }
        __syncthreads();
    }

    const int arow_i = t & 127, akg = t >> 7;
    const bf16* aptr = A + (size_t)(m0 + arow_i) * HH + akg * 8;
    const int bcol = wc * 64 + lane;
    const bf16* bptr = Wt + (size_t)bcol * HH + wr * 8;

    f32x4 acc[4][4] = {};
    uint4 areg, anext;

#define STAGE_B(c, kb)                                                                        \
    _Pragma("unroll") for (int q = 0; q < 2; ++q) {                                           \
        __builtin_amdgcn_global_load_lds((const AS1 void*)(bptr + (kb) + q * 16),             \
                                         (AS3 void*)&L.b[c][q * 512 + w * 64], 16, 0, 0);     \
    }
#define STAGE_A_DMA(c, kb)                                                                    \
    __builtin_amdgcn_global_load_lds((const AS1 void*)(aptr + (kb)),                          \
                                     (AS3 void*)&L.a[c][w * 64], 16, 0, 0);

    // prologue
    STAGE_B(0, 0);
    if (HAS_T) {
        areg = *(const uint4*)(aptr + 0);
        L.a[0][t] = xchunk(areg, L.ca, L.cb, akg * 8);
    } else {
        STAGE_A_DMA(0, 0);
    }
    __syncthreads();

    int c = 0;
    for (int step = 0; step < 8; ++step) {
        const int kn = (step + 1) * 32;
        if (step < 7) {
            STAGE_B(c ^ 1, kn);
            if (HAS_T) anext = *(const uint4*)(aptr + kn);
            else STAGE_A_DMA(c ^ 1, kn);
        }
        short8_t af[4], bfv[4];
#pragma unroll
        for (int m = 0; m < 4; ++m)
            af[m] = *(const short8_t*)&L.a[c][lhi * 128 + wr * 64 + m * 16 + llo];
#pragma unroll
        for (int n = 0; n < 4; ++n)
            bfv[n] = *(const short8_t*)&L.b[c][lhi * 256 + wc * 64 + n * 16 + llo];
#pragma unroll
        for (int m = 0; m < 4; ++m)
#pragma unroll
            for (int n = 0; n < 4; ++n)
                acc[m][n] = __builtin_amdgcn_mfma_f32_16x16x32_bf16(af[m], bfv[n], acc[m][n], 0, 0, 0);
        if (HAS_T && step < 7)
            L.a[c ^ 1][t] = xchunk(anext, L.ca, L.cb, kn + akg * 8);
        __syncthreads();
        c ^= 1;
    }
#undef STAGE_B
#undef STAGE_A_DMA

    // epilogue
    float bias_n[4];
    int col_n[4];
#pragma unroll
    for (int n = 0; n < 4; ++n) {
        col_n[n] = wc * 64 + n * 16 + llo;
        bias_n[n] = bias[col_n[n]];
    }

    if (POOL) {
        // run-length segment-sum into pout[g][col]; rows ascend with (m,j), batch sorted
        int gcur = -1;
        float pacc[4] = {0.f, 0.f, 0.f, 0.f};
#pragma unroll
        for (int m = 0; m < 4; ++m) {
#pragma unroll
            for (int j = 0; j < 4; ++j) {
                int row = m0 + wr * 64 + m * 16 + lhi * 4 + j;
                if (row < M) {
                    int g = pbatch[row];
                    if (g != gcur) {
                        if (gcur >= 0) {
#pragma unroll
                            for (int n = 0; n < 4; ++n)
                                atomicAdd(&pout[(size_t)gcur * HH + col_n[n]], pacc[n]);
                        }
                        gcur = g;
#pragma unroll
                        for (int n = 0; n < 4; ++n) pacc[n] = 0.f;
                    }
#pragma unroll
                    for (int n = 0; n < 4; ++n)
                        pacc[n] += acc[m][n][j] + bias_n[n];
                }
            }
        }
        if (gcur >= 0) {
#pragma unroll
            for (int n = 0; n < 4; ++n)
                atomicAdd(&pout[(size_t)gcur * HH + col_n[n]], pacc[n]);
        }
        return;
    }

    float ps[4] = {0.f, 0.f, 0.f, 0.f}, pq[4] = {0.f, 0.f, 0.f, 0.f};
#pragma unroll
    for (int m = 0; m < 4; ++m) {
#pragma unroll
        for (int j = 0; j < 4; ++j) {
            int row = m0 + wr * 64 + m * 16 + lhi * 4 + j;
            bool valid = row < M;
#pragma unroll
            for (int n = 0; n < 4; ++n) {
                float v = acc[m][n][j] + bias_n[n];
                if (do_relu) v = fmaxf(v, 0.f);
                if (valid) {
                    Out[(size_t)row * HH + col_n[n]] = __float2bfloat16(v);
                    ps[n] += v;
                    pq[n] = fmaf(v, v, pq[n]);
                }
            }
        }
    }

    if (ssum) {
#pragma unroll
        for (int n = 0; n < 4; ++n) {
            float s = ps[n];
            s += __shfl_xor(s, 16);
            s += __shfl_xor(s, 32);
            float q = pq[n];
            q += __shfl_xor(q, 16);
            q += __shfl_xor(q, 32);
            if (lhi == 0) {
                atomicAdd(&ssum[col_n[n]], s);
                atomicAdd(&ssq[col_n[n]], q);
            }
        }
    }
}

static size_t align256(size_t v) { return (v + 255) & ~(size_t)255; }

extern "C" void kernel_launch(void* const* d_in, const int* in_sizes, int n_in,
                              void* d_out, int out_size, void* d_ws, size_t ws_size,
                              hipStream_t stream) {
    const int* x_feat = (const int*)d_in[0];
    const int* ei = (const int*)d_in[1];
    const int* attr = (const int*)d_in[2];
    const int* batch = (const int*)d_in[3];
    const float* atom_emb = (const float*)d_in[4];
    const float* bond_emb = (const float*)d_in[5];
    const float* W1 = (const float*)d_in[6];
    const float* b1 = (const float*)d_in[7];
    const float* g1 = (const float*)d_in[8];
    const float* be1 = (const float*)d_in[9];
    const float* W2 = (const float*)d_in[10];
    const float* b2 = (const float*)d_in[11];
    const float* g2 = (const float*)d_in[12];
    const float* be2 = (const float*)d_in[13];
    const float* outW1 = (const float*)d_in[14];
    const float* outb1 = (const float*)d_in[15];
    const float* outg = (const float*)d_in[16];
    const float* outbe = (const float*)d_in[17];
    const float* outW2 = (const float*)d_in[18];
    const float* outb2 = (const float*)d_in[19];
    float* out = (float*)d_out;

    char* ws = (char*)d_ws;
    const size_t BUF_STRIDE = align256((size_t)NN * HH * 2 + 131072);  // bf16 + GEMM OOB pad
    bf16* bufA = (bf16*)ws;                       // t / node features
    bf16* bufB = (bf16*)(ws + BUF_STRIDE);        // agg
    bf16* bufC = (bf16*)(ws + 2 * BUF_STRIDE);    // y
    char* p = ws + 3 * BUF_STRIDE;
    unsigned int* ebuf = (unsigned int*)p;  p += align256((size_t)EE * sizeof(unsigned int));
    int* deg = (int*)p;
    float* stats = (float*)(p + (size_t)NN * sizeof(int));  // [11][2][256]
    const size_t ZERO_BYTES = (size_t)NN * sizeof(int) + 11 * 512 * sizeof(float);
    p += align256(ZERO_BYTES);
    int* ro = (int*)p;                p += align256((size_t)(NN + 1) * sizeof(int));
    int* cursor = (int*)p;            p += align256((size_t)NN * sizeof(int));
    int* bsum = (int*)p;              p += align256(256 * sizeof(int));
    bf16* combo = (bf16*)p;           p += align256((size_t)512 * HH * sizeof(bf16));
    bf16* wbuf = (bf16*)p;            p += align256((size_t)12 * 65536 * sizeof(bf16));

    const float invN = 1.0f / (float)NN;
    const int EBLK = (EE + 255) / 256;
    const int GBLK = (NN + 127) / 128;   // 391
    const int AGG_GRID = (NN + 3) / 4;
    const int BNR_GRID = (NN + 3) / 4;

    // --- one-time prep ---
    hipMemsetAsync(deg, 0, ZERO_BYTES, stream);
    hipMemsetAsync(d_out, 0, (size_t)GG * HH * sizeof(float), stream);
    k_hist<<<EBLK, 256, 0, stream>>>(ei, deg);
    k_scan_a<<<NCHUNK, 256, 0, stream>>>(deg, ro, bsum);
    k_scan_b<<<1, 256, 0, stream>>>(bsum);
    k_scan_c<<<NCHUNK, 256, 0, stream>>>(ro, bsum, cursor);
    k_scatter<<<(EE + 511) / 512, 256, 0, stream>>>(ei, attr, cursor, ebuf);
    k_combo<<<512, 256, 0, stream>>>(bond_emb, combo);
    k_prepw<<<dim3(8, 8, 12), dim3(32, 8), 0, stream>>>(W1, W2, outW1, outW2, wbuf);
    k_encode<<<NN, 256, 0, stream>>>(x_feat, atom_emb, bufA);

    for (int l = 0; l < LL; ++l) {
        float* s1 = stats + (size_t)(2 * l) * 512;
        float* q1 = s1 + 256;
        float* s2 = stats + (size_t)(2 * l + 1) * 512;
        float* q2 = s2 + 256;
        if (l > 0) {
            float* sp = stats + (size_t)(2 * l - 1) * 512;
            k_bnrelu<<<BNR_GRID, 256, 0, stream>>>(bufA, sp, sp + 256,
                                                   g2 + (size_t)(l - 1) * HH,
                                                   be2 + (size_t)(l - 1) * HH, invN);
        }
        k_aggregate<<<AGG_GRID, 256, 0, stream>>>(bufA, ro, ebuf, combo, bufB);
        // y = agg @ W1 + b1   (+ stats for bn1)
        k_gemm<false, false><<<GBLK, 512, 0, stream>>>(bufB, wbuf + (size_t)l * 65536,
                                                       b1 + (size_t)l * HH, bufC, NN, 0,
                                                       nullptr, nullptr, nullptr, nullptr,
                                                       invN, s1, q1, nullptr, nullptr);
        // t' = relu(T1(y) @ W2 + b2)   (+ stats for bn2)
        k_gemm<true, false><<<GBLK, 512, 0, stream>>>(bufC, wbuf + (size_t)(5 + l) * 65536,
                                                      b2 + (size_t)l * HH, bufA, NN, 1,
                                                      s1, q1, g1 + (size_t)l * HH,
                                                      be1 + (size_t)l * HH, invN, s2, q2,
                                                      nullptr, nullptr);
    }

    // --- head ---
    float* sP = stats + (size_t)9 * 512;   // layer-4 bn2 stats
    float* sH = stats + (size_t)10 * 512;
    float* qH = sH + 256;
    // y = T2(t5) @ outW1 + outb1 (+ stats sH)  — T folded into GEMM, no bnrelu pass
    k_gemm<true, false><<<GBLK, 512, 0, stream>>>(bufA, wbuf + (size_t)10 * 65536, outb1,
                                                  bufB, NN, 0, sP, sP + 256,
                                                  g2 + (size_t)4 * HH, be2 + (size_t)4 * HH,
                                                  invN, sH, qH, nullptr, nullptr);
    // z = T_H(y) @ outW2 + outb2, pooled directly into out
    k_gemm<true, true><<<GBLK, 512, 0, stream>>>(bufB, wbuf + (size_t)11 * 65536, outb2,
                                                 bufC, NN, 0, sH, qH, outg, outbe,
                                                 invN, nullptr, nullptr, batch, out);
}